// Round 19
// baseline (83.144 us; speedup 1.0000x reference)
//
#include <hip/hip_runtime.h>
#include <hip/hip_fp16.h>

typedef float f4 __attribute__((ext_vector_type(4)));
typedef float f32x4 __attribute__((ext_vector_type(4)));
typedef _Float16 f16x8 __attribute__((ext_vector_type(8)));
typedef unsigned int u32x4 __attribute__((ext_vector_type(4)));

#define NPTS 262144
#define CDIM 48
#define DDIM 32
#define KDIM 4
#define G0 512
#define G1 512
#define G2 128

// ws layout (ushort slots) — R14 geometry, f16 values:
// [0, 18432)   : WB — f16 MFMA fragments (36864 B); frags 0..31 staged to LDS,
//                frags 32..35 (4 KB) read from global (coalesced, L1-hot).
// T tables in f16, layout [k][g][c]:
#define T0_OFF 18432                     // 4*512*48 = 98304
#define T1_OFF (18432 + 98304)           // 98304
#define T2_OFF (18432 + 2 * 98304)       // 4*128*48 = 24576 (49152 B -> LDS)

static __forceinline__ __device__ unsigned short f2h(float f) {
    _Float16 h = (_Float16)f;   // RNE
    return __builtin_bit_cast(unsigned short, h);
}
static __forceinline__ __device__ __half2 h2(unsigned int u) {
    return __builtin_bit_cast(__half2, u);
}
static __forceinline__ __device__ unsigned int h2u(__half2 h) {
    return __builtin_bit_cast(unsigned int, h);
}

__global__ void pack_kernel(const int* __restrict__ topk_id,
                            const float* __restrict__ tw,
                            const float* __restrict__ line0,
                            const float* __restrict__ line1,
                            const float* __restrict__ line2,
                            const float* __restrict__ feat0,
                            const float* __restrict__ feat1,
                            const float* __restrict__ feat2,
                            unsigned short* __restrict__ ws) {
    int tid = blockIdx.x * blockDim.x + threadIdx.x;
    int stride = gridDim.x * blockDim.x;

    for (int idx = tid; idx < 3 * 2 * 6 * 64 * 8; idx += stride) {
        int j = idx & 7;
        int l = (idx >> 3) & 63;
        int kt = (idx >> 9) % 6;
        int t = (idx / 3072) % 2;
        int i = idx / 6144;
        int kc = kt * 32 + (l >> 4) * 8 + j;
        int k = kc / 48;
        int c = kc - k * 48;
        int d = t * 16 + (l & 15);
        const float* f = (i == 0) ? feat0 : (i == 1) ? feat1 : feat2;
        ws[idx] = f2h(tw[k] * f[((size_t)topk_id[k] * CDIM + c) * DDIM + d]);
    }
    for (int idx = tid; idx < KDIM * G0 * CDIM; idx += stride) {
        int c = idx % CDIM;
        int g = (idx / CDIM) % G0;
        int k = idx / (CDIM * G0);
        int src = (topk_id[k] * CDIM + c) * G0 + g;
        ws[T0_OFF + idx] = f2h(line0[src]);
        ws[T1_OFF + idx] = f2h(line1[src]);
    }
    for (int idx = tid; idx < KDIM * G2 * CDIM; idx += stride) {
        int c = idx % CDIM;
        int g = (idx / CDIM) % G2;
        int k = idx / (CDIM * G2);
        ws[T2_OFF + idx] = f2h(line2[(topk_id[k] * CDIM + c) * G2 + g]);
    }
}

__global__ __launch_bounds__(512, 4) void main_kernel(const float* __restrict__ pts,
                                                      const unsigned short* __restrict__ ws,
                                                      float* __restrict__ out) {
    // LDS = 32768 (WB frags 0..31) + 49152 (T2) = 81920 B exactly
    // -> 2 blocks/CU (163840 = full 160 KiB pool) -> 16 waves/CU.
    __shared__ __align__(16) unsigned short sWB[16384];
    __shared__ __align__(16) unsigned short sT2[24576];

    const int lane = threadIdx.x & 63;
    const int wave = threadIdx.x >> 6;    // 0..7
    const int row = lane & 15;
    const int h = lane >> 4;

    // Prefetch all 4 tiles' pts (tile stride = 128 points: 8 waves x 16).
    float P0x, P0y, P0z, P1x, P1y, P1z, P2x, P2y, P2z, P3x, P3y, P3z;
    {
        const int pb = blockIdx.x * 512 + wave * 16 + row;
        P0x = pts[(pb + 0 * 128) * 3 + 0]; P0y = pts[(pb + 0 * 128) * 3 + 1]; P0z = pts[(pb + 0 * 128) * 3 + 2];
        P1x = pts[(pb + 1 * 128) * 3 + 0]; P1y = pts[(pb + 1 * 128) * 3 + 1]; P1z = pts[(pb + 1 * 128) * 3 + 2];
        P2x = pts[(pb + 2 * 128) * 3 + 0]; P2y = pts[(pb + 2 * 128) * 3 + 1]; P2z = pts[(pb + 2 * 128) * 3 + 2];
        P3x = pts[(pb + 3 * 128) * 3 + 0]; P3y = pts[(pb + 3 * 128) * 3 + 1]; P3z = pts[(pb + 3 * 128) * 3 + 2];
    }
    asm volatile("" : "+v"(P0x), "+v"(P0y), "+v"(P0z), "+v"(P1x), "+v"(P1y), "+v"(P1z),
                      "+v"(P2x), "+v"(P2y), "+v"(P2z), "+v"(P3x), "+v"(P3y), "+v"(P3z));

    // Stage WB frags 0..31 (2048 x 16B) + T2 (3072 x 16B) into LDS.
    {
        const u32x4* srcW = (const u32x4*)ws;
        u32x4* dstW = (u32x4*)sWB;
        for (int i = threadIdx.x; i < 2048; i += 512) dstW[i] = srcW[i];
        const u32x4* srcT = (const u32x4*)(ws + T2_OFF);
        u32x4* dstT = (u32x4*)sT2;
        for (int i = threadIdx.x; i < 3072; i += 512) dstT[i] = srcT[i];
    }
    __syncthreads();

    const unsigned short* T0 = ws + T0_OFF;
    const unsigned short* T1 = ws + T1_OFF;
    const u32x4* wb = (const u32x4*)sWB;
    const u32x4* wbg = (const u32x4*)ws;   // global fallback for frags 32..35

#define PREP(t, PX, PY, PZ)                                                    \
    float pos0_##t = (PX + 1.0f) * (0.5f * (float)(G0 - 1));                   \
    int i00_##t = min(max((int)floorf(pos0_##t), 0), G0 - 2);                  \
    float w0_##t = pos0_##t - (float)i00_##t;                                  \
    float pos1_##t = (PY + 1.0f) * (0.5f * (float)(G1 - 1));                   \
    int i01_##t = min(max((int)floorf(pos1_##t), 0), G1 - 2);                  \
    float w1_##t = pos1_##t - (float)i01_##t;                                  \
    float pos2_##t = (PZ + 1.0f) * (0.5f * (float)(G2 - 1));                   \
    int i02_##t = min(max((int)floorf(pos2_##t), 0), G2 - 2);                  \
    float w2_##t = pos2_##t - (float)i02_##t;

    PREP(0, P0x, P0y, P0z)
    PREP(1, P1x, P1y, P1z)
    PREP(2, P2x, P2y, P2z)
    PREP(3, P3x, P3y, P3z)

// fragment fetch: LDS for f<32, global (coalesced, L1-hot 4KB) for f>=32
#define FR(p, KT) __builtin_bit_cast(f16x8, (((p) * 6 + (KT)) < 32            \
        ? wb[((p) * 6 + (KT)) * 64 + lane]                                     \
        : wbg[((p) * 6 + (KT)) * 64 + lane]))

#define DECL_LD(n) u32x4 n##a0, n##b0, n##a1, n##b1
#define LOADKT(n, KT, t) {                                                     \
        int kc_ = (KT) * 32 + h * 8;                                           \
        int k_ = kc_ / 48;                                                     \
        int c_ = kc_ - k_ * 48;                                                \
        const unsigned short* t0_ = T0 + (k_ * G0 + i00_##t) * CDIM + c_;      \
        const unsigned short* t1_ = T1 + (k_ * G1 + i01_##t) * CDIM + c_;      \
        n##a0 = *(const u32x4*)t0_;  n##b0 = *(const u32x4*)(t0_ + CDIM);      \
        n##a1 = *(const u32x4*)t1_;  n##b1 = *(const u32x4*)(t1_ + CDIM); }
#define KEEP24()                                                               \
    asm volatile("" : "+v"(q0a0), "+v"(q0b0), "+v"(q0a1), "+v"(q0b1),          \
                      "+v"(q1a0), "+v"(q1b0), "+v"(q1a1), "+v"(q1b1),          \
                      "+v"(q2a0), "+v"(q2b0), "+v"(q2a1), "+v"(q2b1),          \
                      "+v"(q3a0), "+v"(q3b0), "+v"(q3a1), "+v"(q3b1),          \
                      "+v"(q4a0), "+v"(q4b0), "+v"(q4a1), "+v"(q4b1),          \
                      "+v"(q5a0), "+v"(q5b0), "+v"(q5a1), "+v"(q5b1))
#define COMPUTEKT(n, KT, t) {                                                  \
        int kc_ = (KT) * 32 + h * 8;                                           \
        int k_ = kc_ / 48;                                                     \
        int c_ = kc_ - k_ * 48;                                                \
        const unsigned short* t2_ = sT2 + (k_ * G2 + i02_##t) * CDIM + c_;     \
        u32x4 a2 = *(const u32x4*)t2_;                                         \
        u32x4 b2 = *(const u32x4*)(t2_ + CDIM);                                \
        u32x4 pa01, pa02, pa12;                                                \
        _Pragma("unroll")                                                      \
        for (int j = 0; j < 4; ++j) {                                          \
            __half2 x0 = __hfma2(h2(n##b0[j]), W0, __hmul2(h2(n##a0[j]), OM0));\
            __half2 x1 = __hfma2(h2(n##b1[j]), W1, __hmul2(h2(n##a1[j]), OM1));\
            __half2 x2 = __hfma2(h2(b2[j]),   W2, __hmul2(h2(a2[j]),   OM2));  \
            pa01[j] = h2u(__hmul2(x0, x1));                                    \
            pa02[j] = h2u(__hmul2(x0, x2));                                    \
            pa12[j] = h2u(__hmul2(x1, x2));                                    \
        }                                                                      \
        f16x8 fa01 = __builtin_bit_cast(f16x8, pa01);                          \
        f16x8 fa02 = __builtin_bit_cast(f16x8, pa02);                          \
        f16x8 fa12 = __builtin_bit_cast(f16x8, pa12);                          \
        acc00 = __builtin_amdgcn_mfma_f32_16x16x32_f16(FR(0, KT), fa01, acc00, 0, 0, 0); \
        acc01 = __builtin_amdgcn_mfma_f32_16x16x32_f16(FR(1, KT), fa01, acc01, 0, 0, 0); \
        acc10 = __builtin_amdgcn_mfma_f32_16x16x32_f16(FR(2, KT), fa02, acc10, 0, 0, 0); \
        acc11 = __builtin_amdgcn_mfma_f32_16x16x32_f16(FR(3, KT), fa02, acc11, 0, 0, 0); \
        acc20 = __builtin_amdgcn_mfma_f32_16x16x32_f16(FR(4, KT), fa12, acc20, 0, 0, 0); \
        acc21 = __builtin_amdgcn_mfma_f32_16x16x32_f16(FR(5, KT), fa12, acc21, 0, 0, 0); }

#define DO_TILE(t) {                                                           \
        const __half2 W0 = __float2half2_rn(w0_##t), OM0 = __float2half2_rn(1.0f - w0_##t); \
        const __half2 W1 = __float2half2_rn(w1_##t), OM1 = __float2half2_rn(1.0f - w1_##t); \
        const __half2 W2 = __float2half2_rn(w2_##t), OM2 = __float2half2_rn(1.0f - w2_##t); \
        DECL_LD(q0); DECL_LD(q1); DECL_LD(q2);                                 \
        DECL_LD(q3); DECL_LD(q4); DECL_LD(q5);                                 \
        LOADKT(q0, 0, t) LOADKT(q1, 1, t) LOADKT(q2, 2, t)                     \
        LOADKT(q3, 3, t) LOADKT(q4, 4, t) LOADKT(q5, 5, t)                     \
        KEEP24();                                                              \
        f32x4 acc00 = {0.f, 0.f, 0.f, 0.f}, acc01 = acc00;                     \
        f32x4 acc10 = acc00, acc11 = acc00;                                    \
        f32x4 acc20 = acc00, acc21 = acc00;                                    \
        COMPUTEKT(q0, 0, t) COMPUTEKT(q1, 1, t) COMPUTEKT(q2, 2, t)            \
        COMPUTEKT(q3, 3, t) COMPUTEKT(q4, 4, t) COMPUTEKT(q5, 5, t)            \
        float* o = out + (size_t)(blockIdx.x * 512 + (t) * 128 + wave * 16 + row) * 96 + h * 4; \
        *(f4*)(o + 0)  = acc00;                                                \
        *(f4*)(o + 16) = acc01;                                                \
        *(f4*)(o + 32) = acc10;                                                \
        *(f4*)(o + 48) = acc11;                                                \
        *(f4*)(o + 64) = acc20;                                                \
        *(f4*)(o + 80) = acc21; }

    DO_TILE(0)
    DO_TILE(1)
    DO_TILE(2)
    DO_TILE(3)

#undef PREP
#undef FR
#undef DECL_LD
#undef LOADKT
#undef KEEP24
#undef COMPUTEKT
#undef DO_TILE
}

extern "C" void kernel_launch(void* const* d_in, const int* in_sizes, int n_in,
                              void* d_out, int out_size, void* d_ws, size_t ws_size,
                              hipStream_t stream) {
    const float* pts = (const float*)d_in[0];
    const int* topk_id = (const int*)d_in[1];
    const float* tw = (const float*)d_in[2];
    const float* line0 = (const float*)d_in[3];
    const float* line1 = (const float*)d_in[4];
    const float* line2 = (const float*)d_in[5];
    const float* feat0 = (const float*)d_in[6];
    const float* feat1 = (const float*)d_in[7];
    const float* feat2 = (const float*)d_in[8];
    float* out = (float*)d_out;
    unsigned short* ws = (unsigned short*)d_ws;

    pack_kernel<<<512, 256, 0, stream>>>(topk_id, tw, line0, line1, line2,
                                         feat0, feat1, feat2, ws);
    main_kernel<<<NPTS / 512, 512, 0, stream>>>(pts, ws, out);
}

// Round 20
// 60.414 us; speedup vs baseline: 1.3762x; 1.3762x over previous
//
#include <hip/hip_runtime.h>
#include <hip/hip_fp16.h>

typedef float f4 __attribute__((ext_vector_type(4)));
typedef float f32x4 __attribute__((ext_vector_type(4)));
typedef _Float16 f16x8 __attribute__((ext_vector_type(8)));
typedef unsigned int u32x4 __attribute__((ext_vector_type(4)));

#define NPTS 262144
#define CDIM 48
#define DDIM 32
#define KDIM 4
#define G0 512
#define G1 512
#define G2 128

// ws layout (ushort slots) — R14 geometry, f16 values:
// [0, 18432)   : WB — f16 MFMA fragments (36864 B)
// T tables in f16, layout [k][g][c]:
#define T0_OFF 18432                     // 4*512*48 = 98304
#define T1_OFF (18432 + 98304)           // 98304
#define T2_OFF (18432 + 2 * 98304)       // 4*128*48 = 24576 (49152 B -> LDS)

static __forceinline__ __device__ unsigned short f2h(float f) {
    _Float16 h = (_Float16)f;   // RNE
    return __builtin_bit_cast(unsigned short, h);
}
static __forceinline__ __device__ __half2 h2(unsigned int u) {
    return __builtin_bit_cast(__half2, u);
}
static __forceinline__ __device__ unsigned int h2u(__half2 h) {
    return __builtin_bit_cast(unsigned int, h);
}

__global__ void pack_kernel(const int* __restrict__ topk_id,
                            const float* __restrict__ tw,
                            const float* __restrict__ line0,
                            const float* __restrict__ line1,
                            const float* __restrict__ line2,
                            const float* __restrict__ feat0,
                            const float* __restrict__ feat1,
                            const float* __restrict__ feat2,
                            unsigned short* __restrict__ ws) {
    int tid = blockIdx.x * blockDim.x + threadIdx.x;
    int stride = gridDim.x * blockDim.x;

    for (int idx = tid; idx < 3 * 2 * 6 * 64 * 8; idx += stride) {
        int j = idx & 7;
        int l = (idx >> 3) & 63;
        int kt = (idx >> 9) % 6;
        int t = (idx / 3072) % 2;
        int i = idx / 6144;
        int kc = kt * 32 + (l >> 4) * 8 + j;
        int k = kc / 48;
        int c = kc - k * 48;
        int d = t * 16 + (l & 15);
        const float* f = (i == 0) ? feat0 : (i == 1) ? feat1 : feat2;
        ws[idx] = f2h(tw[k] * f[((size_t)topk_id[k] * CDIM + c) * DDIM + d]);
    }
    for (int idx = tid; idx < KDIM * G0 * CDIM; idx += stride) {
        int c = idx % CDIM;
        int g = (idx / CDIM) % G0;
        int k = idx / (CDIM * G0);
        int src = (topk_id[k] * CDIM + c) * G0 + g;
        ws[T0_OFF + idx] = f2h(line0[src]);
        ws[T1_OFF + idx] = f2h(line1[src]);
    }
    for (int idx = tid; idx < KDIM * G2 * CDIM; idx += stride) {
        int c = idx % CDIM;
        int g = (idx / CDIM) % G2;
        int k = idx / (CDIM * G2);
        ws[T2_OFF + idx] = f2h(line2[(topk_id[k] * CDIM + c) * G2 + g]);
    }
}

__global__ __launch_bounds__(512, 1) void main_kernel(const float* __restrict__ pts,
                                                      const unsigned short* __restrict__ ws,
                                                      float* __restrict__ out) {
    __shared__ __align__(16) unsigned short sWB[18432];   // 36864 B
    __shared__ __align__(16) unsigned short sT2[24576];   // 49152 B
    __shared__ __align__(16) float sPts[1536];            // 6144 B: 512 pts xyz

    const int lane = threadIdx.x & 63;
    const int wave = threadIdx.x >> 6;    // 0..7
    const int row = lane & 15;
    const int h = lane >> 4;

    // Stage pts (1 coalesced u32x4 load), WB (2304 x 16B), T2 (3072 x 16B).
    {
        const u32x4* srcP = (const u32x4*)(pts + (size_t)blockIdx.x * 1536);
        u32x4* dstP = (u32x4*)sPts;
        if (threadIdx.x < 384) dstP[threadIdx.x] = srcP[threadIdx.x];
        const u32x4* srcW = (const u32x4*)ws;
        u32x4* dstW = (u32x4*)sWB;
        for (int i = threadIdx.x; i < 2304; i += 512) dstW[i] = srcW[i];
        const u32x4* srcT = (const u32x4*)(ws + T2_OFF);
        u32x4* dstT = (u32x4*)sT2;
        for (int i = threadIdx.x; i < 3072; i += 512) dstT[i] = srcT[i];
    }
    __syncthreads();

    const unsigned short* T0 = ws + T0_OFF;
    const unsigned short* T1 = ws + T1_OFF;
    const u32x4* wb = (const u32x4*)sWB;

#define PREP(t)                                                                \
    float px_##t, py_##t, pz_##t;                                              \
    {                                                                          \
        int pl_ = (t) * 128 + wave * 16 + row;                                 \
        px_##t = sPts[pl_ * 3 + 0];                                            \
        py_##t = sPts[pl_ * 3 + 1];                                            \
        pz_##t = sPts[pl_ * 3 + 2];                                            \
    }                                                                          \
    float pos0_##t = (px_##t + 1.0f) * (0.5f * (float)(G0 - 1));               \
    int i00_##t = min(max((int)floorf(pos0_##t), 0), G0 - 2);                  \
    float w0_##t = pos0_##t - (float)i00_##t;                                  \
    float pos1_##t = (py_##t + 1.0f) * (0.5f * (float)(G1 - 1));               \
    int i01_##t = min(max((int)floorf(pos1_##t), 0), G1 - 2);                  \
    float w1_##t = pos1_##t - (float)i01_##t;                                  \
    float pos2_##t = (pz_##t + 1.0f) * (0.5f * (float)(G2 - 1));               \
    int i02_##t = min(max((int)floorf(pos2_##t), 0), G2 - 2);                  \
    float w2_##t = pos2_##t - (float)i02_##t;

    PREP(0)
    PREP(1)
    PREP(2)
    PREP(3)

#define DECL_LD(n) u32x4 n##a0, n##b0, n##a1, n##b1
#define LOADKT(n, KT, t) {                                                     \
        int kc_ = (KT) * 32 + h * 8;                                           \
        int k_ = kc_ / 48;                                                     \
        int c_ = kc_ - k_ * 48;                                                \
        const unsigned short* t0_ = T0 + (k_ * G0 + i00_##t) * CDIM + c_;      \
        const unsigned short* t1_ = T1 + (k_ * G1 + i01_##t) * CDIM + c_;      \
        n##a0 = *(const u32x4*)t0_;  n##b0 = *(const u32x4*)(t0_ + CDIM);      \
        n##a1 = *(const u32x4*)t1_;  n##b1 = *(const u32x4*)(t1_ + CDIM); }
// Merged keep-alive fence for the tile's 24 global loads (R14 mechanism).
#define KEEP24()                                                               \
    asm volatile("" : "+v"(q0a0), "+v"(q0b0), "+v"(q0a1), "+v"(q0b1),          \
                      "+v"(q1a0), "+v"(q1b0), "+v"(q1a1), "+v"(q1b1),          \
                      "+v"(q2a0), "+v"(q2b0), "+v"(q2a1), "+v"(q2b1),          \
                      "+v"(q3a0), "+v"(q3b0), "+v"(q3a1), "+v"(q3b1),          \
                      "+v"(q4a0), "+v"(q4b0), "+v"(q4a1), "+v"(q4b1),          \
                      "+v"(q5a0), "+v"(q5b0), "+v"(q5a1), "+v"(q5b1))
// Compute: axis-2 rows from LDS (separate pipe, no VMEM requests).
#define COMPUTEKT(n, KT, t) {                                                  \
        int kc_ = (KT) * 32 + h * 8;                                           \
        int k_ = kc_ / 48;                                                     \
        int c_ = kc_ - k_ * 48;                                                \
        const unsigned short* t2_ = sT2 + (k_ * G2 + i02_##t) * CDIM + c_;     \
        u32x4 a2 = *(const u32x4*)t2_;                                         \
        u32x4 b2 = *(const u32x4*)(t2_ + CDIM);                                \
        u32x4 pa01, pa02, pa12;                                                \
        _Pragma("unroll")                                                      \
        for (int j = 0; j < 4; ++j) {                                          \
            __half2 x0 = __hfma2(h2(n##b0[j]), W0, __hmul2(h2(n##a0[j]), OM0));\
            __half2 x1 = __hfma2(h2(n##b1[j]), W1, __hmul2(h2(n##a1[j]), OM1));\
            __half2 x2 = __hfma2(h2(b2[j]),   W2, __hmul2(h2(a2[j]),   OM2));  \
            pa01[j] = h2u(__hmul2(x0, x1));                                    \
            pa02[j] = h2u(__hmul2(x0, x2));                                    \
            pa12[j] = h2u(__hmul2(x1, x2));                                    \
        }                                                                      \
        f16x8 fa01 = __builtin_bit_cast(f16x8, pa01);                          \
        f16x8 fa02 = __builtin_bit_cast(f16x8, pa02);                          \
        f16x8 fa12 = __builtin_bit_cast(f16x8, pa12);                          \
        acc00 = __builtin_amdgcn_mfma_f32_16x16x32_f16(__builtin_bit_cast(f16x8, wb[(0 * 6 + (KT)) * 64 + lane]), fa01, acc00, 0, 0, 0); \
        acc01 = __builtin_amdgcn_mfma_f32_16x16x32_f16(__builtin_bit_cast(f16x8, wb[(1 * 6 + (KT)) * 64 + lane]), fa01, acc01, 0, 0, 0); \
        acc10 = __builtin_amdgcn_mfma_f32_16x16x32_f16(__builtin_bit_cast(f16x8, wb[(2 * 6 + (KT)) * 64 + lane]), fa02, acc10, 0, 0, 0); \
        acc11 = __builtin_amdgcn_mfma_f32_16x16x32_f16(__builtin_bit_cast(f16x8, wb[(3 * 6 + (KT)) * 64 + lane]), fa02, acc11, 0, 0, 0); \
        acc20 = __builtin_amdgcn_mfma_f32_16x16x32_f16(__builtin_bit_cast(f16x8, wb[(4 * 6 + (KT)) * 64 + lane]), fa12, acc20, 0, 0, 0); \
        acc21 = __builtin_amdgcn_mfma_f32_16x16x32_f16(__builtin_bit_cast(f16x8, wb[(5 * 6 + (KT)) * 64 + lane]), fa12, acc21, 0, 0, 0); }

#define DO_TILE(t) {                                                           \
        const __half2 W0 = __float2half2_rn(w0_##t), OM0 = __float2half2_rn(1.0f - w0_##t); \
        const __half2 W1 = __float2half2_rn(w1_##t), OM1 = __float2half2_rn(1.0f - w1_##t); \
        const __half2 W2 = __float2half2_rn(w2_##t), OM2 = __float2half2_rn(1.0f - w2_##t); \
        DECL_LD(q0); DECL_LD(q1); DECL_LD(q2);                                 \
        DECL_LD(q3); DECL_LD(q4); DECL_LD(q5);                                 \
        LOADKT(q0, 0, t) LOADKT(q1, 1, t) LOADKT(q2, 2, t)                     \
        LOADKT(q3, 3, t) LOADKT(q4, 4, t) LOADKT(q5, 5, t)                     \
        KEEP24();                                                              \
        f32x4 acc00 = {0.f, 0.f, 0.f, 0.f}, acc01 = acc00;                     \
        f32x4 acc10 = acc00, acc11 = acc00;                                    \
        f32x4 acc20 = acc00, acc21 = acc00;                                    \
        COMPUTEKT(q0, 0, t) COMPUTEKT(q1, 1, t) COMPUTEKT(q2, 2, t)            \
        COMPUTEKT(q3, 3, t) COMPUTEKT(q4, 4, t) COMPUTEKT(q5, 5, t)            \
        float* o = out + (size_t)(blockIdx.x * 512 + (t) * 128 + wave * 16 + row) * 96 + h * 4; \
        *(f4*)(o + 0)  = acc00;                                                \
        *(f4*)(o + 16) = acc01;                                                \
        *(f4*)(o + 32) = acc10;                                                \
        *(f4*)(o + 48) = acc11;                                                \
        *(f4*)(o + 64) = acc20;                                                \
        *(f4*)(o + 80) = acc21; }

    DO_TILE(0)
    DO_TILE(1)
    DO_TILE(2)
    DO_TILE(3)

#undef PREP
#undef DECL_LD
#undef LOADKT
#undef KEEP24
#undef COMPUTEKT
#undef DO_TILE
}

extern "C" void kernel_launch(void* const* d_in, const int* in_sizes, int n_in,
                              void* d_out, int out_size, void* d_ws, size_t ws_size,
                              hipStream_t stream) {
    const float* pts = (const float*)d_in[0];
    const int* topk_id = (const int*)d_in[1];
    const float* tw = (const float*)d_in[2];
    const float* line0 = (const float*)d_in[3];
    const float* line1 = (const float*)d_in[4];
    const float* line2 = (const float*)d_in[5];
    const float* feat0 = (const float*)d_in[6];
    const float* feat1 = (const float*)d_in[7];
    const float* feat2 = (const float*)d_in[8];
    float* out = (float*)d_out;
    unsigned short* ws = (unsigned short*)d_ws;

    pack_kernel<<<512, 256, 0, stream>>>(topk_id, tw, line0, line1, line2,
                                         feat0, feat1, feat2, ws);
    main_kernel<<<NPTS / 512, 512, 0, stream>>>(pts, ws, out);
}